// Round 1
// baseline (269.682 us; speedup 1.0000x reference)
//
#include <hip/hip_runtime.h>
#include <hip/hip_bf16.h>

#define NB 128
#define NT 1024
#define ND 512
#define NQ 1024
#define NA 128
#define NF 32
#define NK 31
#define CT 32
#define NCHUNK (NT / CT)   // 32

typedef __attribute__((ext_vector_type(8))) short short8;
typedef __attribute__((ext_vector_type(4))) float f32x4;

__device__ __forceinline__ unsigned short f2bf(float f) {
  unsigned int u = __float_as_uint(f);
  u += 0x7fffu + ((u >> 16) & 1u);   // RNE; inputs are finite
  return (unsigned short)(u >> 16);
}

// ---------------------------------------------------------------------------
// Prep: conv (blocks 0..2047), pq = query@Wq (2048..2175), Wt bf16 (2176..2239)
// ---------------------------------------------------------------------------
__global__ __launch_bounds__(256) void lsa_prep(
    const float* __restrict__ query, const float* __restrict__ prev,
    const float* __restrict__ cum, const float* __restrict__ wq,
    const float* __restrict__ wm, const float* __restrict__ ck,
    float* __restrict__ pq_g, float* __restrict__ conv_g,
    unsigned short* __restrict__ wt_g)
{
  __shared__ float sh[2432];
  const int bid = blockIdx.x;
  const int tid = threadIdx.x;
  if (bid < 2048) {
    // 1D conv, SAME pad 15, cat = [prev, cum] channels. 64 t-rows per block.
    const int b = bid >> 4;
    const int t0 = (bid & 15) << 6;
    float* pw = sh;            // 94
    float* cw = sh + 96;       // 94
    float* cks = sh + 192;     // 31*2*32 = 1984
    for (int i = tid; i < 94; i += 256) {
      const int tt = t0 + i - 15;
      const bool ok = (tt >= 0) && (tt < NT);
      pw[i] = ok ? prev[(size_t)b * NT + tt] : 0.f;
      cw[i] = ok ? cum[(size_t)b * NT + tt] : 0.f;
    }
    for (int i = tid; i < NK * 2 * NF; i += 256) cks[i] = ck[i];
    __syncthreads();
    const int f = tid & 31;
    const int tg = tid >> 5;            // 0..7, 8 rows each
    float acc[8];
#pragma unroll
    for (int i = 0; i < 8; ++i) acc[i] = 0.f;
    for (int k = 0; k < NK; ++k) {
      const float c0 = cks[k * 64 + f];
      const float c1 = cks[k * 64 + 32 + f];
#pragma unroll
      for (int i = 0; i < 8; ++i) {
        const int w = tg * 8 + i + k;
        acc[i] += pw[w] * c0 + cw[w] * c1;
      }
    }
#pragma unroll
    for (int i = 0; i < 8; ++i)
      conv_g[((size_t)b * NT + t0 + tg * 8 + i) * NF + f] = acc[i];
  } else if (bid < 2176) {
    // pq[b][a] = sum_q query[b][q] * Wq[q][a]
    const int b = bid - 2048;
    const int a = tid & 127;
    const int h = tid >> 7;
    const float* qrow = query + (size_t)b * NQ;
    float acc = 0.f;
    for (int q = h * 512; q < h * 512 + 512; ++q)
      acc += qrow[q] * wq[(size_t)q * NA + a];
    sh[tid] = acc;
    __syncthreads();
    if (h == 0) pq_g[b * NA + a] = sh[a] + sh[128 + a];
  } else {
    // Wt[a][d] = bf16(Wm[d][a])  (transpose so B-fragments are contiguous in k)
    const int blk = bid - 2176;   // 0..63
    for (int i = blk * 1024 + tid; i < blk * 1024 + 1024; i += 256) {
      const int dd = i >> 7, aa = i & 127;
      wt_g[(size_t)aa * ND + dd] = f2bf(wm[(size_t)dd * NA + aa]);
    }
  }
}

// ---------------------------------------------------------------------------
// Main: per (b, 32-row chunk): keys MFMA + tanh·v -> chunk softmax partial +
// exp-weighted partial context from the LDS bf16 copy (memory read ONCE).
// ---------------------------------------------------------------------------
__global__ __launch_bounds__(512, 4) void lsa_main(
    const float* __restrict__ memory, const int* __restrict__ msl,
    const float* __restrict__ convout, const float* __restrict__ wloc,
    const float* __restrict__ pq_g, const float* __restrict__ v_g,
    const unsigned short* __restrict__ wt_g,
    float* __restrict__ score_g, float* __restrict__ pm_g,
    float* __restrict__ pl_g, float* __restrict__ pctx_g)
{
  const int bid = blockIdx.x;
  const int b = bid >> 5;
  const int ci = bid & 31;
  const int t0 = ci * CT;
  const int len = msl[b];
  if (t0 >= len) return;                 // fully-masked chunk: combine skips it
  const int nvalid = min(CT, len - t0);
  const int tid = threadIdx.x;

  __shared__ __align__(16) unsigned short sv[CT * ND];  // 32 KB, swizzled bf16
  __shared__ float bias_s[CT * 132];                    // padded stride
  __shared__ float conv_s[CT * NF];
  __shared__ float wloc_s[NF * NA];
  __shared__ float pq_s[NA];
  __shared__ float v_s[NA];
  __shared__ float score2[8][CT];
  __shared__ float esc[CT];

  // ---- stage values -> bf16 LDS, XOR-swizzled at 16B granularity ----
  {
    const int r = tid >> 4;        // 0..31
    const int j = tid & 15;
    const float* src = memory + ((size_t)b * NT + (t0 + r)) * ND;
    char* svb = (char*)sv + r * 1024;
    const int sw = (r & 7) << 4;
#pragma unroll
    for (int it = 0; it < 4; ++it) {
      const int e0 = j * 8 + it * 128;
      f32x4 x0 = *(const f32x4*)(src + e0);
      f32x4 x1 = *(const f32x4*)(src + e0 + 4);
      short8 pk;
      pk[0] = (short)f2bf(x0[0]); pk[1] = (short)f2bf(x0[1]);
      pk[2] = (short)f2bf(x0[2]); pk[3] = (short)f2bf(x0[3]);
      pk[4] = (short)f2bf(x1[0]); pk[5] = (short)f2bf(x1[1]);
      pk[6] = (short)f2bf(x1[2]); pk[7] = (short)f2bf(x1[3]);
      *(short8*)(svb + ((e0 * 2) ^ sw)) = pk;
    }
  }
  for (int i = tid; i < CT * NF; i += 512)
    conv_s[i] = convout[((size_t)b * NT + t0) * NF + i];
  for (int i = tid; i < NF * NA; i += 512) wloc_s[i] = wloc[i];
  if (tid < NA) { pq_s[tid] = pq_g[b * NA + tid]; v_s[tid] = v_g[tid]; }
  __syncthreads();

  // ---- bias[t][a] = pq[a] + sum_f conv[t][f]*wloc[f][a] ----
  {
    const int a = tid & 127;
    const int tg = tid >> 7;       // 0..3, 8 rows each
    float acc[8];
    const float pqa = pq_s[a];
#pragma unroll
    for (int i = 0; i < 8; ++i) acc[i] = pqa;
    for (int f = 0; f < NF; ++f) {
      const float wf = wloc_s[f * NA + a];
#pragma unroll
      for (int i = 0; i < 8; ++i) acc[i] += conv_s[(tg * 8 + i) * NF + f] * wf;
    }
#pragma unroll
    for (int i = 0; i < 8; ++i) bias_s[(tg * 8 + i) * 132 + a] = acc[i];
  }
  __syncthreads();

  // ---- keys GEMM: 32(t) x 512(d) x 128(a); 8 waves each own 16 cols ----
  const int wid = tid >> 6;
  const int lane = tid & 63;
  const int lhi = lane >> 4, llo = lane & 15;
  {
    const unsigned short* bp = wt_g + (size_t)(wid * 16 + llo) * ND + lhi * 8;
    const int sw = (llo & 7) << 4;
    const char* a0b = (const char*)sv + llo * 1024;
    const char* a1b = (const char*)sv + (16 + llo) * 1024;
    f32x4 acc0 = {0.f, 0.f, 0.f, 0.f};
    f32x4 acc1 = {0.f, 0.f, 0.f, 0.f};
#pragma unroll
    for (int kf = 0; kf < 16; ++kf) {
      const short8 bb = *(const short8*)(bp + kf * 32);
      const int bo = (kf * 64 + lhi * 16) ^ sw;
      const short8 a0 = *(const short8*)(a0b + bo);
      const short8 a1 = *(const short8*)(a1b + bo);
      acc0 = __builtin_amdgcn_mfma_f32_16x16x32_bf16(a0, bb, acc0, 0, 0, 0);
      acc1 = __builtin_amdgcn_mfma_f32_16x16x32_bf16(a1, bb, acc1, 0, 0, 0);
    }
    // epilogue: tanh(keys+bias)*v, reduce over this wave's 16 cols
    const int c = wid * 16 + llo;
    const float vc = v_s[c];
#pragma unroll
    for (int mf = 0; mf < 2; ++mf) {
      const f32x4 av = mf ? acc1 : acc0;
#pragma unroll
      for (int rg = 0; rg < 4; ++rg) {
        const int r = mf * 16 + lhi * 4 + rg;
        float e = tanhf(av[rg] + bias_s[r * 132 + c]) * vc;
#pragma unroll
        for (int off = 1; off < 16; off <<= 1) e += __shfl_xor(e, off);
        if (llo == 0) score2[wid][r] = e;
      }
    }
  }
  __syncthreads();

  // ---- chunk softmax partial (wave 0) ----
  if (wid == 0) {
    const int t = lane;
    float s = -3.4e38f;
    if (t < CT) {
      s = 0.f;
#pragma unroll
      for (int w = 0; w < 8; ++w) s += score2[w][t];
      score_g[(size_t)b * NT + t0 + t] = s;   // raw score for finalize
    }
    float sm = (t < nvalid) ? s : -3.4e38f;
#pragma unroll
    for (int off = 1; off < 64; off <<= 1) sm = fmaxf(sm, __shfl_xor(sm, off));
    const float e = (t < nvalid) ? expf(s - sm) : 0.f;
    float l = e;
#pragma unroll
    for (int off = 1; off < 64; off <<= 1) l += __shfl_xor(l, off);
    if (t < CT) esc[t] = e;
    if (lane == 0) { pm_g[bid] = sm; pl_g[bid] = l; }
  }
  __syncthreads();

  // ---- partial context from the SAME LDS copy (no HBM re-read) ----
  {
    const int d = tid;   // 512 threads == D
    float acc = 0.f;
    const char* svb = (const char*)sv;
    for (int t = 0; t < nvalid; ++t) {
      const unsigned short u =
          *(const unsigned short*)(svb + t * 1024 + ((2 * d) ^ ((t & 7) << 4)));
      acc += esc[t] * __uint_as_float((unsigned int)u << 16);
    }
    pctx_g[(size_t)bid * ND + d] = acc;
  }
}

// ---------------------------------------------------------------------------
// Combine: merge 32 chunk partials per batch; write context, attn, new_cum.
// ---------------------------------------------------------------------------
__global__ __launch_bounds__(256) void lsa_comb(
    const int* __restrict__ msl, const float* __restrict__ score_g,
    const float* __restrict__ cum, const float* __restrict__ pm_g,
    const float* __restrict__ pl_g, const float* __restrict__ pctx_g,
    float* __restrict__ out)
{
  const int b = blockIdx.x;
  const int tid = threadIdx.x;
  const int len = msl[b];
  const int nck = (len + CT - 1) / CT;
  __shared__ float coef[NCHUNK];
  __shared__ float MLsh[2];
  if (tid < 64) {
    const int i = tid;
    const float m = (i < nck) ? pm_g[b * NCHUNK + i] : -3.4e38f;
    const float l = (i < nck) ? pl_g[b * NCHUNK + i] : 0.f;
    float M = m;
#pragma unroll
    for (int off = 1; off < 64; off <<= 1) M = fmaxf(M, __shfl_xor(M, off));
    const float c = expf(m - M);   // 0 for invalid chunks
    float L = l * c;
#pragma unroll
    for (int off = 1; off < 64; off <<= 1) L += __shfl_xor(L, off);
    if (i < NCHUNK) coef[i] = c;
    if (i == 0) { MLsh[0] = M; MLsh[1] = L; }
  }
  __syncthreads();
  const float M = MLsh[0];
  const float Linv = 1.f / MLsh[1];
  for (int d = tid; d < ND; d += 256) {
    float acc = 0.f;
    for (int i = 0; i < nck; ++i)
      acc += pctx_g[((size_t)b * NCHUNK + i) * ND + d] * coef[i];
    out[(size_t)b * ND + d] = acc * Linv;
  }
  float* attn_o = out + (size_t)NB * ND;
  float* cum_o = attn_o + (size_t)NB * NT;
  for (int t = tid; t < NT; t += 256) {
    float w = 0.f;
    if (t < len) w = expf(score_g[(size_t)b * NT + t] - M) * Linv;
    attn_o[(size_t)b * NT + t] = w;
    cum_o[(size_t)b * NT + t] = w + cum[(size_t)b * NT + t];
  }
}

extern "C" void kernel_launch(void* const* d_in, const int* in_sizes, int n_in,
                              void* d_out, int out_size, void* d_ws, size_t ws_size,
                              hipStream_t stream) {
  const float* query  = (const float*)d_in[0];
  const float* prev   = (const float*)d_in[1];
  const float* cum    = (const float*)d_in[2];
  const float* memory = (const float*)d_in[3];
  const int*   msl    = (const int*)d_in[4];
  const float* wq     = (const float*)d_in[5];
  const float* wm     = (const float*)d_in[6];
  const float* ck     = (const float*)d_in[7];
  const float* wloc   = (const float*)d_in[8];
  const float* vv     = (const float*)d_in[9];
  float* out = (float*)d_out;

  // workspace layout (floats), ~24.8 MB total
  float* ws = (float*)d_ws;
  float* score_g = ws;                        // 131072
  float* pq_g    = ws + 131072;               // 16384
  float* pm_g    = ws + 147456;               // 4096
  float* pl_g    = ws + 151552;               // 4096
  float* pctx_g  = ws + 155648;               // 2097152
  float* conv_g  = ws + 2252800;              // 4194304
  unsigned short* wt_g = (unsigned short*)(ws + 6447104);  // 65536 bf16

  lsa_prep<<<2240, 256, 0, stream>>>(query, prev, cum, wq, wm, ck,
                                     pq_g, conv_g, wt_g);
  lsa_main<<<NB * NCHUNK, 512, 0, stream>>>(memory, msl, conv_g, wloc, pq_g, vv,
                                            wt_g, score_g, pm_g, pl_g, pctx_g);
  lsa_comb<<<NB, 256, 0, stream>>>(msl, score_g, cum, pm_g, pl_g, pctx_g, out);
}

// Round 2
// 108.739 us; speedup vs baseline: 2.4801x; 2.4801x over previous
//
#include <hip/hip_runtime.h>
#include <hip/hip_bf16.h>

#define NB 128
#define NT 1024
#define ND 512
#define NDA 576   // 512 (memory) + 64 (im2col window, 62 used + 2 zero pad)
#define NQ 1024
#define NA 128
#define NF 32
#define NK 31
#define CT 32
#define NCHUNK (NT / CT)   // 32

typedef __attribute__((ext_vector_type(8))) short short8;
typedef __attribute__((ext_vector_type(4))) short short4_t;
typedef __attribute__((ext_vector_type(4))) float f32x4;

__device__ __forceinline__ unsigned short f2bf(float f) {
  unsigned int u = __float_as_uint(f);
  u += 0x7fffu + ((u >> 16) & 1u);   // RNE; inputs are finite
  return (unsigned short)(u >> 16);
}

// ---------------------------------------------------------------------------
// Prep: pq partials (blocks 0..511), Wm^T -> bf16 (512..575), W2 = ck@Wloc
// (576..583). All well-parallelized; no serial latency chains.
// ---------------------------------------------------------------------------
__global__ __launch_bounds__(256) void lsa_prep(
    const float* __restrict__ query, const float* __restrict__ wq,
    const float* __restrict__ wm, const float* __restrict__ ck,
    const float* __restrict__ wloc,
    float* __restrict__ pq_part, unsigned short* __restrict__ wt_g)
{
  const int bid = blockIdx.x;
  const int tid = threadIdx.x;
  if (bid < 512) {
    // pq partial: b = bid>>2, q-chunk qg = bid&3 (256 q's)
    __shared__ float qs[256];
    __shared__ float red[256];
    const int b = bid >> 2;
    const int qg = bid & 3;
    qs[tid] = query[(size_t)b * NQ + qg * 256 + tid];
    __syncthreads();
    const int a = tid & 127;
    const int h = tid >> 7;
    const float* wqp = wq + (size_t)(qg * 256 + h * 128) * NA + a;
    float acc = 0.f;
#pragma unroll 8
    for (int qi = 0; qi < 128; ++qi)
      acc += qs[h * 128 + qi] * wqp[(size_t)qi * NA];
    red[tid] = acc;
    __syncthreads();
    if (h == 0) pq_part[((size_t)b * 4 + qg) * NA + a] = red[a] + red[128 + a];
  } else if (bid < 576) {
    // Wt[a][d] = bf16(Wm[d][a]), row stride NDA
    const int blk = bid - 512;   // 0..63, 8 d-rows each
    for (int i = blk * 1024 + tid; i < blk * 1024 + 1024; i += 256) {
      const int dd = i >> 7, aa = i & 127;
      wt_g[(size_t)aa * NDA + dd] = f2bf(wm[(size_t)dd * NA + aa]);
    }
  } else {
    // W2[w][a] = sum_f ck[k][ch][f]*wloc[f][a], w = 2k+ch; rows 62,63 = 0.
    __shared__ float wl_s[NF * NA];    // 16 KB
    __shared__ float ck_s[NK * 2 * NF];
    const int blk = bid - 576;         // 0..7, 8 w's each
    for (int i = tid; i < NF * NA; i += 256) wl_s[i] = wloc[i];
    for (int i = tid; i < NK * 2 * NF; i += 256) ck_s[i] = ck[i];
    __syncthreads();
    const int a = tid & 127;
    const int h = tid >> 7;
#pragma unroll
    for (int wi = 0; wi < 4; ++wi) {
      const int w = blk * 8 + h * 4 + wi;
      float acc = 0.f;
      if (w < 62) {
        const int k = w >> 1, ch = w & 1;
#pragma unroll
        for (int f = 0; f < NF; ++f)
          acc += ck_s[k * 64 + ch * 32 + f] * wl_s[f * NA + a];
      }
      wt_g[(size_t)a * NDA + 512 + w] = f2bf(acc);
    }
  }
}

// ---------------------------------------------------------------------------
// Main: per (b, 32-row chunk): augmented GEMM [values|window]@[Wt;W2] via
// MFMA -> tanh(.+pq)*v -> chunk softmax partial + partial context from the
// same LDS bf16 copy. memory is read from HBM exactly once.
// ---------------------------------------------------------------------------
__global__ __launch_bounds__(512, 4) void lsa_main(
    const float* __restrict__ memory, const int* __restrict__ msl,
    const float* __restrict__ prev, const float* __restrict__ cum,
    const float* __restrict__ pq_part, const float* __restrict__ v_g,
    const unsigned short* __restrict__ wt_g,
    float* __restrict__ score_g, float* __restrict__ pm_g,
    float* __restrict__ pl_g, float* __restrict__ pctx_g)
{
  const int bid = blockIdx.x;
  const int b = bid >> 5;
  const int ci = bid & 31;
  const int t0 = ci * CT;
  const int len = msl[b];
  if (t0 >= len) return;                 // fully-masked chunk: combine skips it
  const int nvalid = min(CT, len - t0);
  const int tid = threadIdx.x;

  __shared__ __align__(16) unsigned short sv[CT * NDA];  // 36 KB, swizzled bf16
  __shared__ float pwin_s[62];
  __shared__ float cwin_s[62];
  __shared__ float pq_s[NA];
  __shared__ float v_s[NA];
  __shared__ float score2[8][CT];
  __shared__ float esc[CT];

  // ---- stage values -> bf16 LDS (first 1024B of each 1152B row), swizzled --
  {
    const int r = tid >> 4;        // 0..31
    const int j = tid & 15;
    const float* src = memory + ((size_t)b * NT + (t0 + r)) * ND;
    char* svb = (char*)sv + r * 1152;
    const int sw = (r & 7) << 4;
#pragma unroll
    for (int it = 0; it < 4; ++it) {
      const int e0 = j * 8 + it * 128;
      f32x4 x0 = *(const f32x4*)(src + e0);
      f32x4 x1 = *(const f32x4*)(src + e0 + 4);
      short8 pk;
      pk[0] = (short)f2bf(x0[0]); pk[1] = (short)f2bf(x0[1]);
      pk[2] = (short)f2bf(x0[2]); pk[3] = (short)f2bf(x0[3]);
      pk[4] = (short)f2bf(x1[0]); pk[5] = (short)f2bf(x1[1]);
      pk[6] = (short)f2bf(x1[2]); pk[7] = (short)f2bf(x1[3]);
      *(short8*)(svb + ((e0 * 2) ^ sw)) = pk;
    }
  }
  // prev/cum windows [t0-15, t0+46] (62 each)
  if (tid < 124) {
    const int j = tid >> 1, chn = tid & 1;
    const int tt = t0 - 15 + j;
    const float val = (tt >= 0 && tt < NT)
        ? (chn ? cum : prev)[(size_t)b * NT + tt] : 0.f;
    (chn ? cwin_s : pwin_s)[j] = val;
  }
  if (tid >= 384) {   // separate wave: pq (sum 4 partials) and v
    const int a = tid - 384;
    v_s[a] = v_g[a];
    const float* pp = pq_part + (size_t)b * 4 * NA + a;
    pq_s[a] = pp[0] + pp[NA] + pp[2 * NA] + pp[3 * NA];
  }
  __syncthreads();

  // ---- build im2col X into cols 512..575 (bytes 1024..1151 of each row) ----
  {
    const int t = tid >> 4;
    const int w0 = (tid & 15) * 4;
    short4_t x4;
#pragma unroll
    for (int i = 0; i < 4; ++i) {
      const int w = w0 + i;
      float val = 0.f;
      if (w < 62) val = (w & 1) ? cwin_s[t + (w >> 1)] : pwin_s[t + (w >> 1)];
      x4[i] = (short)f2bf(val);
    }
    char* dst = (char*)sv + t * 1152 + ((1024 + w0 * 2) ^ ((t & 7) << 4));
    *(short4_t*)dst = x4;
  }
  __syncthreads();

  // ---- augmented GEMM: 32(t) x 576(k) x 128(a); 8 waves each own 16 cols ---
  const int wid = tid >> 6;
  const int lane = tid & 63;
  const int lhi = lane >> 4, llo = lane & 15;
  {
    const unsigned short* bp = wt_g + (size_t)(wid * 16 + llo) * NDA + lhi * 8;
    const int sw = (llo & 7) << 4;
    const char* a0b = (const char*)sv + llo * 1152;
    const char* a1b = (const char*)sv + (16 + llo) * 1152;
    f32x4 acc0 = {0.f, 0.f, 0.f, 0.f};
    f32x4 acc1 = {0.f, 0.f, 0.f, 0.f};
#pragma unroll
    for (int kf = 0; kf < 18; ++kf) {
      const short8 bb = *(const short8*)(bp + kf * 32);
      const int bo = (kf * 64 + lhi * 16) ^ sw;
      const short8 a0 = *(const short8*)(a0b + bo);
      const short8 a1 = *(const short8*)(a1b + bo);
      acc0 = __builtin_amdgcn_mfma_f32_16x16x32_bf16(a0, bb, acc0, 0, 0, 0);
      acc1 = __builtin_amdgcn_mfma_f32_16x16x32_bf16(a1, bb, acc1, 0, 0, 0);
    }
    // epilogue: tanh(keys + ploc + pq)*v, reduce over this wave's 16 cols
    const int c = wid * 16 + llo;
    const float vc = v_s[c];
    const float pqc = pq_s[c];
#pragma unroll
    for (int mf = 0; mf < 2; ++mf) {
      const f32x4 av = mf ? acc1 : acc0;
#pragma unroll
      for (int rg = 0; rg < 4; ++rg) {
        const int r = mf * 16 + lhi * 4 + rg;
        float e = tanhf(av[rg] + pqc) * vc;
#pragma unroll
        for (int off = 1; off < 16; off <<= 1) e += __shfl_xor(e, off);
        if (llo == 0) score2[wid][r] = e;
      }
    }
  }
  __syncthreads();

  // ---- chunk softmax partial (wave 0) ----
  if (wid == 0) {
    const int t = lane;
    float s = -3.4e38f;
    if (t < CT) {
      s = 0.f;
#pragma unroll
      for (int w = 0; w < 8; ++w) s += score2[w][t];
      score_g[(size_t)b * NT + t0 + t] = s;   // raw score for finalize
    }
    float sm = (t < nvalid) ? s : -3.4e38f;
#pragma unroll
    for (int off = 1; off < 64; off <<= 1) sm = fmaxf(sm, __shfl_xor(sm, off));
    const float e = (t < nvalid) ? expf(s - sm) : 0.f;
    float l = e;
#pragma unroll
    for (int off = 1; off < 64; off <<= 1) l += __shfl_xor(l, off);
    if (t < CT) esc[t] = e;
    if (lane == 0) { pm_g[bid] = sm; pl_g[bid] = l; }
  }
  __syncthreads();

  // ---- partial context from the SAME LDS copy (no HBM re-read) ----
  {
    const int d = tid;   // 512 threads == D
    float acc = 0.f;
    const char* svb = (const char*)sv;
    for (int t = 0; t < nvalid; ++t) {
      const unsigned short u =
          *(const unsigned short*)(svb + t * 1152 + ((2 * d) ^ ((t & 7) << 4)));
      acc += esc[t] * __uint_as_float((unsigned int)u << 16);
    }
    pctx_g[(size_t)bid * ND + d] = acc;
  }
}

// ---------------------------------------------------------------------------
// Combine: merge 32 chunk partials per batch; write context, attn, new_cum.
// ---------------------------------------------------------------------------
__global__ __launch_bounds__(256) void lsa_comb(
    const int* __restrict__ msl, const float* __restrict__ score_g,
    const float* __restrict__ cum, const float* __restrict__ pm_g,
    const float* __restrict__ pl_g, const float* __restrict__ pctx_g,
    float* __restrict__ out)
{
  const int b = blockIdx.x;
  const int tid = threadIdx.x;
  const int len = msl[b];
  const int nck = (len + CT - 1) / CT;
  __shared__ float coef[NCHUNK];
  __shared__ float MLsh[2];
  if (tid < 64) {
    const int i = tid;
    const float m = (i < nck) ? pm_g[b * NCHUNK + i] : -3.4e38f;
    const float l = (i < nck) ? pl_g[b * NCHUNK + i] : 0.f;
    float M = m;
#pragma unroll
    for (int off = 1; off < 64; off <<= 1) M = fmaxf(M, __shfl_xor(M, off));
    const float c = expf(m - M);   // 0 for invalid chunks
    float L = l * c;
#pragma unroll
    for (int off = 1; off < 64; off <<= 1) L += __shfl_xor(L, off);
    if (i < NCHUNK) coef[i] = c;
    if (i == 0) { MLsh[0] = M; MLsh[1] = L; }
  }
  __syncthreads();
  const float M = MLsh[0];
  const float Linv = 1.f / MLsh[1];
  for (int d = tid; d < ND; d += 256) {
    float acc = 0.f;
    for (int i = 0; i < nck; ++i)
      acc += pctx_g[((size_t)b * NCHUNK + i) * ND + d] * coef[i];
    out[(size_t)b * ND + d] = acc * Linv;
  }
  float* attn_o = out + (size_t)NB * ND;
  float* cum_o = attn_o + (size_t)NB * NT;
  for (int t = tid; t < NT; t += 256) {
    float w = 0.f;
    if (t < len) w = expf(score_g[(size_t)b * NT + t] - M) * Linv;
    attn_o[(size_t)b * NT + t] = w;
    cum_o[(size_t)b * NT + t] = w + cum[(size_t)b * NT + t];
  }
}

extern "C" void kernel_launch(void* const* d_in, const int* in_sizes, int n_in,
                              void* d_out, int out_size, void* d_ws, size_t ws_size,
                              hipStream_t stream) {
  const float* query  = (const float*)d_in[0];
  const float* prev   = (const float*)d_in[1];
  const float* cum    = (const float*)d_in[2];
  const float* memory = (const float*)d_in[3];
  const int*   msl    = (const int*)d_in[4];
  const float* wq     = (const float*)d_in[5];
  const float* wm     = (const float*)d_in[6];
  const float* ck     = (const float*)d_in[7];
  const float* wloc   = (const float*)d_in[8];
  const float* vv     = (const float*)d_in[9];
  float* out = (float*)d_out;

  // workspace layout (floats), ~9.4 MB total
  float* ws = (float*)d_ws;
  float* score_g = ws;                        // 131072
  float* pm_g    = ws + 131072;               // 4096
  float* pl_g    = ws + 135168;               // 4096
  float* pctx_g  = ws + 139264;               // 2097152
  float* pq_part = ws + 2236416;              // 65536
  unsigned short* wt_g = (unsigned short*)(ws + 2301952);  // 128*576 bf16

  lsa_prep<<<584, 256, 0, stream>>>(query, wq, wm, ck, wloc, pq_part, wt_g);
  lsa_main<<<NB * NCHUNK, 512, 0, stream>>>(memory, msl, prev, cum, pq_part, vv,
                                            wt_g, score_g, pm_g, pl_g, pctx_g);
  lsa_comb<<<NB, 256, 0, stream>>>(msl, score_g, cum, pm_g, pl_g, pctx_g, out);
}

// Round 3
// 106.159 us; speedup vs baseline: 2.5404x; 1.0243x over previous
//
#include <hip/hip_runtime.h>
#include <hip/hip_bf16.h>

#define NB 128
#define NT 1024
#define ND 512
#define NDA 576   // 512 (memory) + 64 (im2col window, 62 used + 2 zero pad)
#define NQ 1024
#define NA 128
#define NF 32
#define NK 31
#define CT 32
#define NCHUNK (NT / CT)   // 32

typedef __attribute__((ext_vector_type(8))) short short8;
typedef __attribute__((ext_vector_type(4))) float f32x4;
typedef __attribute__((ext_vector_type(4))) unsigned int u32x4;
typedef __attribute__((ext_vector_type(2))) unsigned int u32x2;

__device__ __forceinline__ unsigned short f2bf(float f) {
  unsigned int u = __float_as_uint(f);
  u += 0x7fffu + ((u >> 16) & 1u);   // RNE; inputs are finite
  return (unsigned short)(u >> 16);
}

// packed f32x2 -> bf16x2 in one VALU op; D[15:0]=bf16(lo), D[31:16]=bf16(hi)
__device__ __forceinline__ unsigned int cvt_pk_bf16(float lo, float hi) {
  unsigned int r;
  asm("v_cvt_pk_bf16_f32 %0, %1, %2" : "=v"(r) : "v"(lo), "v"(hi));
  return r;
}

// ---------------------------------------------------------------------------
// Prep: pq partials (blocks 0..511), Wm^T -> bf16 (512..575), W2 = ck@Wloc
// (576..583). All well-parallelized; no serial latency chains.
// ---------------------------------------------------------------------------
__global__ __launch_bounds__(256) void lsa_prep(
    const float* __restrict__ query, const float* __restrict__ wq,
    const float* __restrict__ wm, const float* __restrict__ ck,
    const float* __restrict__ wloc,
    float* __restrict__ pq_part, unsigned short* __restrict__ wt_g)
{
  const int bid = blockIdx.x;
  const int tid = threadIdx.x;
  if (bid < 512) {
    // pq partial: b = bid>>2, q-chunk qg = bid&3 (256 q's)
    __shared__ float qs[256];
    __shared__ float red[256];
    const int b = bid >> 2;
    const int qg = bid & 3;
    qs[tid] = query[(size_t)b * NQ + qg * 256 + tid];
    __syncthreads();
    const int a = tid & 127;
    const int h = tid >> 7;
    const float* wqp = wq + (size_t)(qg * 256 + h * 128) * NA + a;
    float acc = 0.f;
#pragma unroll 8
    for (int qi = 0; qi < 128; ++qi)
      acc += qs[h * 128 + qi] * wqp[(size_t)qi * NA];
    red[tid] = acc;
    __syncthreads();
    if (h == 0) pq_part[((size_t)b * 4 + qg) * NA + a] = red[a] + red[128 + a];
  } else if (bid < 576) {
    // Wt[a][d] = bf16(Wm[d][a]), row stride NDA
    const int blk = bid - 512;   // 0..63, 8 d-rows each
    for (int i = blk * 1024 + tid; i < blk * 1024 + 1024; i += 256) {
      const int dd = i >> 7, aa = i & 127;
      wt_g[(size_t)aa * NDA + dd] = f2bf(wm[(size_t)dd * NA + aa]);
    }
  } else {
    // W2[w][a] = sum_f ck[k][ch][f]*wloc[f][a], w = 2k+ch; rows 62,63 = 0.
    __shared__ float wl_s[NF * NA];    // 16 KB
    __shared__ float ck_s[NK * 2 * NF];
    const int blk = bid - 576;         // 0..7, 8 w's each
    for (int i = tid; i < NF * NA; i += 256) wl_s[i] = wloc[i];
    for (int i = tid; i < NK * 2 * NF; i += 256) ck_s[i] = ck[i];
    __syncthreads();
    const int a = tid & 127;
    const int h = tid >> 7;
#pragma unroll
    for (int wi = 0; wi < 4; ++wi) {
      const int w = blk * 8 + h * 4 + wi;
      float acc = 0.f;
      if (w < 62) {
        const int k = w >> 1, ch = w & 1;
#pragma unroll
        for (int f = 0; f < NF; ++f)
          acc += ck_s[k * 64 + ch * 32 + f] * wl_s[f * NA + a];
      }
      wt_g[(size_t)a * NDA + 512 + w] = f2bf(acc);
    }
  }
}

// ---------------------------------------------------------------------------
// Main: per (b, 32-row chunk): augmented GEMM [values|window]@[Wt;W2] via
// MFMA -> tanh(.+pq)*v -> chunk softmax partial + partial context from the
// same LDS bf16 copy. memory is read from HBM exactly once.
// ---------------------------------------------------------------------------
__global__ __launch_bounds__(512, 6) void lsa_main(
    const float* __restrict__ memory, const int* __restrict__ msl,
    const float* __restrict__ prev, const float* __restrict__ cum,
    const float* __restrict__ pq_part, const float* __restrict__ v_g,
    const unsigned short* __restrict__ wt_g,
    float* __restrict__ score_g, float* __restrict__ pm_g,
    float* __restrict__ pl_g, float* __restrict__ pctx_g)
{
  const int bid = blockIdx.x;
  const int b = bid >> 5;
  const int ci = bid & 31;
  const int t0 = ci * CT;
  const int len = msl[b];
  if (t0 >= len) return;                 // fully-masked chunk: combine skips it
  const int nvalid = min(CT, len - t0);
  const int tid = threadIdx.x;

  __shared__ __align__(16) unsigned short sv[CT * NDA];  // 36 KB, swizzled bf16
  __shared__ float pwin_s[62];
  __shared__ float cwin_s[62];
  __shared__ float pq_s[NA];
  __shared__ float v_s[NA];
  __shared__ float score2[8][CT];
  __shared__ float esc[CT];

  // ---- stage values -> bf16 LDS (first 1024B of each 1152B row), swizzled --
  {
    const int r = tid >> 4;        // 0..31
    const int j = tid & 15;
    const float* src = memory + ((size_t)b * NT + (t0 + r)) * ND;
    char* svb = (char*)sv + r * 1152;
    const int sw = (r & 7) << 4;
#pragma unroll
    for (int it = 0; it < 4; ++it) {
      const int e0 = j * 8 + it * 128;
      f32x4 x0 = *(const f32x4*)(src + e0);
      f32x4 x1 = *(const f32x4*)(src + e0 + 4);
      u32x4 pk;
      pk[0] = cvt_pk_bf16(x0[0], x0[1]);
      pk[1] = cvt_pk_bf16(x0[2], x0[3]);
      pk[2] = cvt_pk_bf16(x1[0], x1[1]);
      pk[3] = cvt_pk_bf16(x1[2], x1[3]);
      *(u32x4*)(svb + ((e0 * 2) ^ sw)) = pk;
    }
  }
  // prev/cum windows [t0-15, t0+46] (62 each)
  if (tid < 124) {
    const int j = tid >> 1, chn = tid & 1;
    const int tt = t0 - 15 + j;
    const float val = (tt >= 0 && tt < NT)
        ? (chn ? cum : prev)[(size_t)b * NT + tt] : 0.f;
    (chn ? cwin_s : pwin_s)[j] = val;
  }
  if (tid >= 384) {   // separate wave: pq (sum 4 partials) and v
    const int a = tid - 384;
    v_s[a] = v_g[a];
    const float* pp = pq_part + (size_t)b * 4 * NA + a;
    pq_s[a] = pp[0] + pp[NA] + pp[2 * NA] + pp[3 * NA];
  }
  __syncthreads();

  // ---- build im2col X into cols 512..575 (bytes 1024..1151 of each row) ----
  {
    const int t = tid >> 4;
    const int w0 = (tid & 15) * 4;
    float xv[4];
#pragma unroll
    for (int i = 0; i < 4; ++i) {
      const int w = w0 + i;
      xv[i] = 0.f;
      if (w < 62) xv[i] = (w & 1) ? cwin_s[t + (w >> 1)] : pwin_s[t + (w >> 1)];
    }
    u32x2 pk;
    pk[0] = cvt_pk_bf16(xv[0], xv[1]);
    pk[1] = cvt_pk_bf16(xv[2], xv[3]);
    char* dst = (char*)sv + t * 1152 + ((1024 + w0 * 2) ^ ((t & 7) << 4));
    *(u32x2*)dst = pk;
  }
  __syncthreads();

  // ---- augmented GEMM: 32(t) x 576(k) x 128(a); 8 waves each own 16 cols ---
  const int wid = tid >> 6;
  const int lane = tid & 63;
  const int lhi = lane >> 4, llo = lane & 15;
  {
    const unsigned short* bp = wt_g + (size_t)(wid * 16 + llo) * NDA + lhi * 8;
    const int sw = (llo & 7) << 4;
    const char* a0b = (const char*)sv + llo * 1152;
    const char* a1b = (const char*)sv + (16 + llo) * 1152;
    f32x4 acc0 = {0.f, 0.f, 0.f, 0.f};
    f32x4 acc1 = {0.f, 0.f, 0.f, 0.f};
#pragma unroll
    for (int kf = 0; kf < 18; ++kf) {
      const short8 bb = *(const short8*)(bp + kf * 32);
      const int bo = (kf * 64 + lhi * 16) ^ sw;
      const short8 a0 = *(const short8*)(a0b + bo);
      const short8 a1 = *(const short8*)(a1b + bo);
      acc0 = __builtin_amdgcn_mfma_f32_16x16x32_bf16(a0, bb, acc0, 0, 0, 0);
      acc1 = __builtin_amdgcn_mfma_f32_16x16x32_bf16(a1, bb, acc1, 0, 0, 0);
    }
    // epilogue: tanh(keys + ploc + pq)*v, reduce over this wave's 16 cols
    const int c = wid * 16 + llo;
    const float vc = v_s[c];
    const float pqc = pq_s[c];
#pragma unroll
    for (int mf = 0; mf < 2; ++mf) {
      const f32x4 av = mf ? acc1 : acc0;
#pragma unroll
      for (int rg = 0; rg < 4; ++rg) {
        const int r = mf * 16 + lhi * 4 + rg;
        float e = tanhf(av[rg] + pqc) * vc;
#pragma unroll
        for (int off = 1; off < 16; off <<= 1) e += __shfl_xor(e, off);
        if (llo == 0) score2[wid][r] = e;
      }
    }
  }
  __syncthreads();

  // ---- chunk softmax partial (wave 0) ----
  if (wid == 0) {
    const int t = lane;
    float s = -3.4e38f;
    if (t < CT) {
      s = 0.f;
#pragma unroll
      for (int w = 0; w < 8; ++w) s += score2[w][t];
      score_g[(size_t)b * NT + t0 + t] = s;   // raw score for finalize
    }
    float sm = (t < nvalid) ? s : -3.4e38f;
#pragma unroll
    for (int off = 1; off < 64; off <<= 1) sm = fmaxf(sm, __shfl_xor(sm, off));
    const float e = (t < nvalid) ? expf(s - sm) : 0.f;
    float l = e;
#pragma unroll
    for (int off = 1; off < 64; off <<= 1) l += __shfl_xor(l, off);
    if (t < CT) esc[t] = e;
    if (lane == 0) { pm_g[bid] = sm; pl_g[bid] = l; }
  }
  __syncthreads();

  // ---- partial context from the SAME LDS copy, vectorized ds_read_b128 ----
  // wave w owns d-groups g = 8w..8w+7 (8 d's each); lanes split t 4-ways.
  {
    const int sub = lane & 7;            // t-part: t = sub, sub+8, +16, +24
    const int gi = lane >> 3;            // 0..7
    const int g = wid * 8 + gi;          // d-group, d0 = 8g
    const char* svb = (const char*)sv;
    float acc[8];
#pragma unroll
    for (int i = 0; i < 8; ++i) acc[i] = 0.f;
#pragma unroll
    for (int tp = 0; tp < 4; ++tp) {
      const int t = tp * 8 + sub;
      const float e = esc[t];            // broadcast; 0 for t >= nvalid
      const short8 u = *(const short8*)(svb + t * 1152 + 16 * (g ^ sub));
#pragma unroll
      for (int i = 0; i < 8; ++i)
        acc[i] += e * __uint_as_float(((unsigned int)(unsigned short)u[i]) << 16);
    }
#pragma unroll
    for (int off = 1; off < 8; off <<= 1) {
#pragma unroll
      for (int i = 0; i < 8; ++i) acc[i] += __shfl_xor(acc[i], off);
    }
    if (sub == 0) {
      float* dst = pctx_g + (size_t)bid * ND + g * 8;
      f32x4 lo = {acc[0], acc[1], acc[2], acc[3]};
      f32x4 hi = {acc[4], acc[5], acc[6], acc[7]};
      *(f32x4*)dst = lo;
      *(f32x4*)(dst + 4) = hi;
    }
  }
}

// ---------------------------------------------------------------------------
// Combine: merge 32 chunk partials per batch; write context, attn, new_cum.
// ---------------------------------------------------------------------------
__global__ __launch_bounds__(512) void lsa_comb(
    const int* __restrict__ msl, const float* __restrict__ score_g,
    const float* __restrict__ cum, const float* __restrict__ pm_g,
    const float* __restrict__ pl_g, const float* __restrict__ pctx_g,
    float* __restrict__ out)
{
  const int b = blockIdx.x;
  const int tid = threadIdx.x;
  const int len = msl[b];
  const int nck = (len + CT - 1) / CT;
  __shared__ float coef[NCHUNK];
  __shared__ float MLsh[2];
  if (tid < 64) {
    const int i = tid;
    const float m = (i < nck) ? pm_g[b * NCHUNK + i] : -3.4e38f;
    const float l = (i < nck) ? pl_g[b * NCHUNK + i] : 0.f;
    float M = m;
#pragma unroll
    for (int off = 1; off < 64; off <<= 1) M = fmaxf(M, __shfl_xor(M, off));
    const float c = expf(m - M);   // 0 for invalid chunks
    float L = l * c;
#pragma unroll
    for (int off = 1; off < 64; off <<= 1) L += __shfl_xor(L, off);
    if (i < NCHUNK) coef[i] = c;
    if (i == 0) { MLsh[0] = M; MLsh[1] = L; }
  }
  __syncthreads();
  const float M = MLsh[0];
  const float Linv = 1.f / MLsh[1];
  {
    const int d = tid;   // 512 threads == D
    float acc = 0.f;
    for (int i = 0; i < nck; ++i)
      acc += pctx_g[((size_t)b * NCHUNK + i) * ND + d] * coef[i];
    out[(size_t)b * ND + d] = acc * Linv;
  }
  float* attn_o = out + (size_t)NB * ND;
  float* cum_o = attn_o + (size_t)NB * NT;
#pragma unroll
  for (int it = 0; it < 2; ++it) {
    const int t = it * 512 + tid;
    float w = 0.f;
    if (t < len) w = expf(score_g[(size_t)b * NT + t] - M) * Linv;
    attn_o[(size_t)b * NT + t] = w;
    cum_o[(size_t)b * NT + t] = w + cum[(size_t)b * NT + t];
  }
}

extern "C" void kernel_launch(void* const* d_in, const int* in_sizes, int n_in,
                              void* d_out, int out_size, void* d_ws, size_t ws_size,
                              hipStream_t stream) {
  const float* query  = (const float*)d_in[0];
  const float* prev   = (const float*)d_in[1];
  const float* cum    = (const float*)d_in[2];
  const float* memory = (const float*)d_in[3];
  const int*   msl    = (const int*)d_in[4];
  const float* wq     = (const float*)d_in[5];
  const float* wm     = (const float*)d_in[6];
  const float* ck     = (const float*)d_in[7];
  const float* wloc   = (const float*)d_in[8];
  const float* vv     = (const float*)d_in[9];
  float* out = (float*)d_out;

  // workspace layout (floats), ~9.4 MB total
  float* ws = (float*)d_ws;
  float* score_g = ws;                        // 131072
  float* pm_g    = ws + 131072;               // 4096
  float* pl_g    = ws + 135168;               // 4096
  float* pctx_g  = ws + 139264;               // 2097152
  float* pq_part = ws + 2236416;              // 65536
  unsigned short* wt_g = (unsigned short*)(ws + 2301952);  // 128*576 bf16

  lsa_prep<<<584, 256, 0, stream>>>(query, wq, wm, ck, wloc, pq_part, wt_g);
  lsa_main<<<NB * NCHUNK, 512, 0, stream>>>(memory, msl, prev, cum, pq_part, vv,
                                            wt_g, score_g, pm_g, pl_g, pctx_g);
  lsa_comb<<<NB, 512, 0, stream>>>(msl, score_g, cum, pm_g, pl_g, pctx_g, out);
}